// Round 11
// baseline (71.045 us; speedup 1.0000x reference)
//
#include <hip/hip_runtime.h>
#include <math.h>

#define T_COLS 147456   // N_R*3*N_D*C = 1024*3*16*3
#define NU 49152        // T_COLS/3: u = (part*1024 + r)*16 + d
#define KSPLIT 4

// ws layout (float offsets)
#define OFF_ME      0                              // 256*8
#define OFF_THETA   2048                           // 8*3*49152 (permuted theta_t)
#define OFF_MULP    (OFF_THETA + 8*T_COLS)         // 8*3*1024*16
#define OFF_ADDSUM  (OFF_MULP + 8*3*1024*16)       // 8*3*1024
#define OFF_Q       (OFF_ADDSUM + 8*3*1024)        // 8*3*1024
#define OFF_PART    (OFF_Q + 8*3*1024)             // 4*8*147456 = 18.9 MB

// fast tanh: 1 - 2/(exp(2x)+1); abs err ~2e-7, inf-safe
__device__ __forceinline__ float tanh_fast(float x) {
    float e = __expf(2.f * x);
    return 1.f - 2.f * __builtin_amdgcn_rcpf(e + 1.f);
}

// K1: me[k][b] = mean over 64 spatial of patch_emb[b,:,:,k]
__global__ __launch_bounds__(1024) void k1_mean(const float* __restrict__ pe,
                                                float* __restrict__ me) {
    int b = blockIdx.x;                     // 8
    int k = threadIdx.x & 255, qd = threadIdx.x >> 8;
    const float* p = pe + (size_t)b * 16384 + qd * 4096 + k;
    float s = 0.f;
#pragma unroll
    for (int i = 0; i < 16; i++) s += p[i * 256];
    __shared__ float part[4][256];
    part[qd][k] = s;
    __syncthreads();
    if (threadIdx.x < 256) {
        float v = part[0][k] + part[1][k] + part[2][k] + part[3][k];
        me[k * 8 + b] = v * (1.f / 64.f);
    }
}

// K2: partial GEMV, k-split 4 for 36 waves/CU (latency-concurrency fix).
// 3072 blocks x 192 threads. Block (cw,s): cols cw*192..+192, k in [s*64,s*64+64).
// part[(s*8+b)*T_COLS + t] = sum_{k in slice} me[b][k] * w[k][t]
__global__ __launch_bounds__(192) void k2_gemm(const float* __restrict__ w,
                                               const float* __restrict__ me,
                                               float* __restrict__ part) {
    __shared__ __align__(16) float lme[2048];   // [k][b]
    int tid = threadIdx.x;
    for (int i = tid; i < 2048; i += 192) lme[i] = me[i];
    __syncthreads();

    int bid = blockIdx.x;
    int s = bid & 3, cw = bid >> 2;             // s: k-slice, cw: column block
    int t = cw * 192 + tid;
    const float* wp = w + t;
    const int k0 = s * 64;

    float acc[8];
#pragma unroll
    for (int b = 0; b < 8; b++) acc[b] = 0.f;

#pragma unroll 32
    for (int kk = 0; kk < 64; kk++) {
        int k = k0 + kk;
        float wv = wp[(size_t)k * T_COLS];
        const float4* m4 = reinterpret_cast<const float4*>(&lme[k * 8]);
        float4 m0 = m4[0], m1 = m4[1];
        acc[0] += m0.x * wv;
        acc[1] += m0.y * wv;
        acc[2] += m0.z * wv;
        acc[3] += m0.w * wv;
        acc[4] += m1.x * wv;
        acc[5] += m1.y * wv;
        acc[6] += m1.z * wv;
        acc[7] += m1.w * wv;
    }
#pragma unroll
    for (int b = 0; b < 8; b++)
        part[(size_t)(s * 8 + b) * T_COLS + t] = acc[b];
}

// kR: tt[(b*3+c)*NU + u] = sum_s part[s][b][t] + bt[t], t = 3u+c.
// 768 blocks x 192 threads; partials L2-resident. Permuted write via LDS.
__global__ __launch_bounds__(192) void kR(const float* __restrict__ part,
                                          const float* __restrict__ bt,
                                          float* __restrict__ tt) {
    __shared__ float lt[8][192];
    int tid = threadIdx.x;
    int t = blockIdx.x * 192 + tid;
    float bv = bt[t];

    float acc[8];
#pragma unroll
    for (int b = 0; b < 8; b++) acc[b] = bv;
#pragma unroll
    for (int s = 0; s < KSPLIT; s++) {
#pragma unroll
        for (int b = 0; b < 8; b++)
            acc[b] += part[(size_t)(s * 8 + b) * T_COLS + t];
    }
#pragma unroll
    for (int b = 0; b < 8; b++) lt[b][tid] = acc[b];
    __syncthreads();

    int u0 = blockIdx.x * 64;
    int j = tid & 63;
    int c = tid >> 6;                    // 0..2 (wave-uniform)
#pragma unroll
    for (int b = 0; b < 8; b++) {
        float v = lt[b][j * 3 + c];
        tt[(size_t)(b * 3 + c) * NU + u0 + j] = v;
    }
}

// kC: fused softmax + tanh*sm + A/s reduction + p-iteration + q.
// One block per (b,c), 1024 threads (1 range row each). All theta reads coalesced.
#define MVL_STRIDE 1028
__global__ __launch_bounds__(1024) void kC(const float* __restrict__ tt,
                                           float* __restrict__ mulp,
                                           float* __restrict__ addsum,
                                           float* __restrict__ q) {
    int bc = blockIdx.x;                 // 24
    int r = threadIdx.x;                 // 0..1023
    int lane = r & 63, wv = r >> 6;      // 16 waves
    const float4* base = reinterpret_cast<const float4*>(tt + (size_t)bc * NU);

    __shared__ float redm[16 * 16];          // [wave][d]
    __shared__ float gm[16], ginv[16];
    __shared__ float mvl[16 * MVL_STRIDE];   // transposed mv, padded
    __shared__ float sred[1024];
    __shared__ float Ash[256];
    __shared__ float svl[16], pl[16];

    // ---- 1) mix load (part 2, float4-coalesced) + block max per d ----
    float mx[16];
    {
        float4 x0 = base[8192 + r * 4 + 0];
        float4 x1 = base[8192 + r * 4 + 1];
        float4 x2 = base[8192 + r * 4 + 2];
        float4 x3 = base[8192 + r * 4 + 3];
        mx[0] = x0.x; mx[1] = x0.y; mx[2] = x0.z; mx[3] = x0.w;
        mx[4] = x1.x; mx[5] = x1.y; mx[6] = x1.z; mx[7] = x1.w;
        mx[8] = x2.x; mx[9] = x2.y; mx[10] = x2.z; mx[11] = x2.w;
        mx[12] = x3.x; mx[13] = x3.y; mx[14] = x3.z; mx[15] = x3.w;
    }
    {
        float wred[16];
#pragma unroll
        for (int d = 0; d < 16; d++) wred[d] = mx[d];
#pragma unroll
        for (int m = 32; m > 0; m >>= 1)
#pragma unroll
            for (int d = 0; d < 16; d++)
                wred[d] = fmaxf(wred[d], __shfl_xor(wred[d], m));
        if (lane == 0) {
#pragma unroll
            for (int d = 0; d < 16; d++) redm[wv * 16 + d] = wred[d];
        }
    }
    __syncthreads();
    if (r < 16) {
        float m = -1e30f;
#pragma unroll
        for (int w = 0; w < 16; w++) m = fmaxf(m, redm[w * 16 + r]);
        gm[r] = m;
    }
    __syncthreads();

    // ---- 2) exp + block sum per d ----
    {
        float wred[16];
#pragma unroll
        for (int d = 0; d < 16; d++) {
            mx[d] = __expf(mx[d] - gm[d]);
            wred[d] = mx[d];
        }
#pragma unroll
        for (int m = 32; m > 0; m >>= 1)
#pragma unroll
            for (int d = 0; d < 16; d++)
                wred[d] += __shfl_xor(wred[d], m);
        if (lane == 0) {
#pragma unroll
            for (int d = 0; d < 16; d++) redm[wv * 16 + d] = wred[d];
        }
    }
    __syncthreads();
    if (r < 16) {
        float s = 0.f;
#pragma unroll
        for (int w = 0; w < 16; w++) s += redm[w * 16 + r];
        ginv[r] = 1.f / s;
    }
    __syncthreads();
#pragma unroll
    for (int d = 0; d < 16; d++) mx[d] *= ginv[d];   // mx = softmax sm[r][d]

    // ---- 3) add phase (part 1) ----
    float asum = 0.f;
    {
        float4 a0 = base[4096 + r * 4 + 0];
        float4 a1 = base[4096 + r * 4 + 1];
        float4 a2 = base[4096 + r * 4 + 2];
        float4 a3 = base[4096 + r * 4 + 3];
        float av[16];
        av[0] = a0.x; av[1] = a0.y; av[2] = a0.z; av[3] = a0.w;
        av[4] = a1.x; av[5] = a1.y; av[6] = a1.z; av[7] = a1.w;
        av[8] = a2.x; av[9] = a2.y; av[10] = a2.z; av[11] = a2.w;
        av[12] = a3.x; av[13] = a3.y; av[14] = a3.z; av[15] = a3.w;
#pragma unroll
        for (int d = 0; d < 16; d++) asum += tanh_fast(av[d]) * mx[d];
    }
    addsum[(size_t)bc * 1024 + r] = asum;
    sred[r] = asum;

    // ---- 4) mul phase (part 0) ----
    float mv[16];
    {
        float4 m0 = base[r * 4 + 0];
        float4 m1 = base[r * 4 + 1];
        float4 m2 = base[r * 4 + 2];
        float4 m3 = base[r * 4 + 3];
        mv[0] = m0.x; mv[1] = m0.y; mv[2] = m0.z; mv[3] = m0.w;
        mv[4] = m1.x; mv[5] = m1.y; mv[6] = m1.z; mv[7] = m1.w;
        mv[8] = m2.x; mv[9] = m2.y; mv[10] = m2.z; mv[11] = m2.w;
        mv[12] = m3.x; mv[13] = m3.y; mv[14] = m3.z; mv[15] = m3.w;
#pragma unroll
        for (int d = 0; d < 16; d++) mv[d] = tanh_fast(mv[d]) * mx[d];
    }
    {
        float4* mp = reinterpret_cast<float4*>(&mulp[((size_t)bc * 1024 + r) * 16]);
        mp[0] = make_float4(mv[0], mv[1], mv[2], mv[3]);
        mp[1] = make_float4(mv[4], mv[5], mv[6], mv[7]);
        mp[2] = make_float4(mv[8], mv[9], mv[10], mv[11]);
        mp[3] = make_float4(mv[12], mv[13], mv[14], mv[15]);
    }
#pragma unroll
    for (int d = 0; d < 16; d++) mvl[d * MVL_STRIDE + r] = mv[d];
    __syncthreads();

    // ---- 5) A[dd][d], sv[dd] ----
    if (r < 256) {
        int dd = r >> 4, d = r & 15;
        int di = dd >> 2, dj = dd & 3;
        const float* bse = &mvl[d * MVL_STRIDE + di * 256 + dj * 8];
        float s = 0.f;
        for (int a = 0; a < 8; a++) {
#pragma unroll
            for (int e = 0; e < 8; e++) s += bse[a * 32 + e];
        }
        Ash[r] = s * (1.f / 64.f);
    }
    if (r < 16) {
        int di = r >> 2, dj = r & 3;
        float s = 0.f;
        for (int a = 0; a < 8; a++)
#pragma unroll
            for (int e = 0; e < 8; e++) s += sred[di * 256 + a * 32 + dj * 8 + e];
        svl[r] = s * (1.f / 64.f);
    }
    __syncthreads();

    // ---- 6) p_8 iteration on wave 0, 16-lane shfl broadcast ----
    if (r < 64) {
        int d2 = r & 15;
        float arow[16];
#pragma unroll
        for (int d = 0; d < 16; d++) arow[d] = Ash[d2 * 16 + d];
        float sv = svl[d2];
        float pd = 0.f;
        for (int it = 0; it < 8; it++) {
            float x = sv;
#pragma unroll
            for (int d = 0; d < 16; d++) x += arow[d] * __shfl(pd, d, 16);
            pd = x;
        }
        if (r < 16) pl[r] = pd;
    }
    __syncthreads();

    // ---- 7) q[r] ----
    {
        float x = asum;
#pragma unroll
        for (int d = 0; d < 16; d++) x += mv[d] * pl[d];
        q[(size_t)bc * 1024 + r] = x;
    }
}

// K5: final image. Block = (b, ri): 8 rows x 256 cols x 3 c. q staged in LDS.
__global__ __launch_bounds__(512) void k5_final(const float* __restrict__ mulp,
                                                const float* __restrict__ addsum,
                                                const float* __restrict__ q,
                                                float* __restrict__ out) {
    int blk = blockIdx.x;                 // 256
    int b = blk >> 5, ri = blk & 31;
    int tid = threadIdx.x;                // 512
    __shared__ float ql[3072];            // q for 3 channels of this b
    for (int i = tid; i < 3072; i += 512) ql[i] = q[(size_t)b * 3072 + i];
    __syncthreads();

    int h = tid >> 6;                     // 0..7 (wave-uniform)
    int rj = (tid >> 1) & 31;             // 0..31
    int wh = tid & 1;                     // w-half
    int r = ri * 32 + rj;

    float mr[3][16];
    float as[3];
#pragma unroll
    for (int c = 0; c < 3; c++) {
        const float4* mp4 = reinterpret_cast<const float4*>(
            &mulp[((size_t)(b * 3 + c) * 1024 + r) * 16]);
        float4 v0 = mp4[0], v1 = mp4[1], v2 = mp4[2], v3 = mp4[3];
        mr[c][0] = v0.x; mr[c][1] = v0.y; mr[c][2] = v0.z; mr[c][3] = v0.w;
        mr[c][4] = v1.x; mr[c][5] = v1.y; mr[c][6] = v1.z; mr[c][7] = v1.w;
        mr[c][8] = v2.x; mr[c][9] = v2.y; mr[c][10] = v2.z; mr[c][11] = v2.w;
        mr[c][12] = v3.x; mr[c][13] = v3.y; mr[c][14] = v3.z; mr[c][15] = v3.w;
        as[c] = addsum[(size_t)(b * 3 + c) * 1024 + r];
    }

    float acc[3][4];
#pragma unroll
    for (int c = 0; c < 3; c++)
#pragma unroll
        for (int w = 0; w < 4; w++) acc[c][w] = as[c];

#pragma unroll
    for (int di = 0; di < 4; di++) {
        int qrow = (di * 8 + h) * 32;
#pragma unroll
        for (int dj = 0; dj < 4; dj++) {
#pragma unroll
            for (int c = 0; c < 3; c++) {
                float m = mr[c][di * 4 + dj];
                const float* qb = &ql[c * 1024 + qrow + dj * 8 + wh * 4];
                acc[c][0] += m * qb[0];
                acc[c][1] += m * qb[1];
                acc[c][2] += m * qb[2];
                acc[c][3] += m * qb[3];
            }
        }
    }

    int i = ri * 8 + h;
    int j0 = rj * 8 + wh * 4;
    float4* ob = reinterpret_cast<float4*>(
        &out[((size_t)(b * 256 + i) * 256 + j0) * 3]);
    ob[0] = make_float4(acc[0][0], acc[1][0], acc[2][0], acc[0][1]);
    ob[1] = make_float4(acc[1][1], acc[2][1], acc[0][2], acc[1][2]);
    ob[2] = make_float4(acc[2][2], acc[0][3], acc[1][3], acc[2][3]);
}

extern "C" void kernel_launch(void* const* d_in, const int* in_sizes, int n_in,
                              void* d_out, int out_size, void* d_ws, size_t ws_size,
                              hipStream_t stream) {
    const float* pe = (const float*)d_in[0];   // (8,8,8,256)
    const float* w  = (const float*)d_in[1];   // (256,147456)
    const float* bt = (const float*)d_in[2];   // (147456,)
    float* ws = (float*)d_ws;

    float* me     = ws + OFF_ME;
    float* tt     = ws + OFF_THETA;
    float* mulp   = ws + OFF_MULP;
    float* addsum = ws + OFF_ADDSUM;
    float* q      = ws + OFF_Q;
    float* part   = ws + OFF_PART;
    float* out = (float*)d_out;

    k1_mean<<<8, 1024, 0, stream>>>(pe, me);
    k2_gemm<<<768 * KSPLIT, 192, 0, stream>>>(w, me, part);    // 3072 blocks, ~30 waves/CU
    kR<<<T_COLS / 192, 192, 0, stream>>>(part, bt, tt);        // 768 blocks
    kC<<<24, 1024, 0, stream>>>(tt, mulp, addsum, q);
    k5_final<<<256, 512, 0, stream>>>(mulp, addsum, q, out);
}

// Round 12
// 60.536 us; speedup vs baseline: 1.1736x; 1.1736x over previous
//
#include <hip/hip_runtime.h>
#include <math.h>

#define T_COLS 147456   // N_R*3*N_D*C = 1024*3*16*3
#define BS 8
#define NU 49152        // T_COLS/3: u = (part*1024 + r)*16 + d

// ws layout (float offsets)
#define OFF_ME      0                              // 256*8
#define OFF_THETA   2048                           // 8*3*49152 (permuted theta_t)
#define OFF_MULP    (OFF_THETA + BS*T_COLS)        // 8*3*1024*16
#define OFF_ADDSUM  (OFF_MULP + 8*3*1024*16)       // 8*3*1024
#define OFF_Q       (OFF_ADDSUM + 8*3*1024)        // 8*3*1024

// fast tanh: 1 - 2/(exp(2x)+1); abs err ~2e-7, inf-safe
__device__ __forceinline__ float tanh_fast(float x) {
    float e = __expf(2.f * x);
    return 1.f - 2.f * __builtin_amdgcn_rcpf(e + 1.f);
}

// K1: me[k][b] = mean over 64 spatial of patch_emb[b,:,:,k]
__global__ __launch_bounds__(1024) void k1_mean(const float* __restrict__ pe,
                                                float* __restrict__ me) {
    int b = blockIdx.x;                     // 8
    int k = threadIdx.x & 255, qd = threadIdx.x >> 8;
    const float* p = pe + (size_t)b * 16384 + qd * 4096 + k;
    float s = 0.f;
#pragma unroll
    for (int i = 0; i < 16; i++) s += p[i * 256];
    __shared__ float part[4][256];
    part[qd][k] = s;
    __syncthreads();
    if (threadIdx.x < 256) {
        float v = part[0][k] + part[1][k] + part[2][k] + part[3][k];
        me[k * 8 + b] = v * (1.f / 64.f);
    }
}

// K2: theta_t[(b*3+c)*49152 + u] = sum_k me[b][k]*w[k][t] + bt[t], t = 3u+c.
// 768 blocks x 192 threads = exactly 3 blocks/CU.
// XCD-aware column swizzle: blocks land on XCD bid%8; remap so each XCD owns
// a CONTIGUOUS 73.7 KB window of every k-row (8 wide DRAM streams instead of
// 768 scattered 768B bursts at 576KB stride). A/B vs R6: isolates DRAM
// row-activate locality; zero extra traffic.
__global__ __launch_bounds__(192) void k2_gemm(const float* __restrict__ w,
                                               const float* __restrict__ bt,
                                               const float* __restrict__ me,
                                               float* __restrict__ tt) {
    __shared__ __align__(16) float lme[2048];   // [k][b]
    __shared__ float lt[8][192];
    int tid = threadIdx.x;
    for (int i = tid; i < 2048; i += 192) lme[i] = me[i];
    __syncthreads();

    int bid = blockIdx.x;
    int cw = (bid & 7) * 96 + (bid >> 3);   // XCD-contiguous column slab
    int t = cw * 192 + tid;
    const float* wp = w + t;
    float bv = bt[t];

    float acc[8];
#pragma unroll
    for (int b = 0; b < 8; b++) acc[b] = 0.f;

#pragma unroll 32
    for (int k = 0; k < 256; k++) {
        float wv = wp[(size_t)k * T_COLS];
        const float4* m4 = reinterpret_cast<const float4*>(&lme[k * 8]);
        float4 m0 = m4[0], m1 = m4[1];
        acc[0] += m0.x * wv;
        acc[1] += m0.y * wv;
        acc[2] += m0.z * wv;
        acc[3] += m0.w * wv;
        acc[4] += m1.x * wv;
        acc[5] += m1.y * wv;
        acc[6] += m1.z * wv;
        acc[7] += m1.w * wv;
    }
#pragma unroll
    for (int b = 0; b < 8; b++) lt[b][tid] = acc[b] + bv;
    __syncthreads();

    // permuted write: wave c handles channel c; 64 lanes = 64 consecutive u
    int u0 = cw * 64;
    int j = tid & 63;
    int c = tid >> 6;                    // 0..2 (wave-uniform)
#pragma unroll
    for (int b = 0; b < 8; b++) {
        float v = lt[b][j * 3 + c];
        tt[(size_t)(b * 3 + c) * NU + u0 + j] = v;
    }
}

// kC: fused softmax + tanh*sm + A/s reduction + p-iteration + q.
// One block per (b,c), 1024 threads (1 range row each). All theta reads coalesced.
#define MVL_STRIDE 1028
__global__ __launch_bounds__(1024) void kC(const float* __restrict__ tt,
                                           float* __restrict__ mulp,
                                           float* __restrict__ addsum,
                                           float* __restrict__ q) {
    int bc = blockIdx.x;                 // 24
    int r = threadIdx.x;                 // 0..1023
    int lane = r & 63, wv = r >> 6;      // 16 waves
    const float4* base = reinterpret_cast<const float4*>(tt + (size_t)bc * NU);

    __shared__ float redm[16 * 16];          // [wave][d]
    __shared__ float gm[16], ginv[16];
    __shared__ float mvl[16 * MVL_STRIDE];   // transposed mv, padded
    __shared__ float sred[1024];
    __shared__ float Ash[256];
    __shared__ float svl[16], pl[16];

    // ---- 1) mix load (part 2, float4-coalesced) + block max per d ----
    float mx[16];
    {
        float4 x0 = base[8192 + r * 4 + 0];
        float4 x1 = base[8192 + r * 4 + 1];
        float4 x2 = base[8192 + r * 4 + 2];
        float4 x3 = base[8192 + r * 4 + 3];
        mx[0] = x0.x; mx[1] = x0.y; mx[2] = x0.z; mx[3] = x0.w;
        mx[4] = x1.x; mx[5] = x1.y; mx[6] = x1.z; mx[7] = x1.w;
        mx[8] = x2.x; mx[9] = x2.y; mx[10] = x2.z; mx[11] = x2.w;
        mx[12] = x3.x; mx[13] = x3.y; mx[14] = x3.z; mx[15] = x3.w;
    }
    {
        float wred[16];
#pragma unroll
        for (int d = 0; d < 16; d++) wred[d] = mx[d];
#pragma unroll
        for (int m = 32; m > 0; m >>= 1)
#pragma unroll
            for (int d = 0; d < 16; d++)
                wred[d] = fmaxf(wred[d], __shfl_xor(wred[d], m));
        if (lane == 0) {
#pragma unroll
            for (int d = 0; d < 16; d++) redm[wv * 16 + d] = wred[d];
        }
    }
    __syncthreads();
    if (r < 16) {
        float m = -1e30f;
#pragma unroll
        for (int w = 0; w < 16; w++) m = fmaxf(m, redm[w * 16 + r]);
        gm[r] = m;
    }
    __syncthreads();

    // ---- 2) exp + block sum per d ----
    {
        float wred[16];
#pragma unroll
        for (int d = 0; d < 16; d++) {
            mx[d] = __expf(mx[d] - gm[d]);
            wred[d] = mx[d];
        }
#pragma unroll
        for (int m = 32; m > 0; m >>= 1)
#pragma unroll
            for (int d = 0; d < 16; d++)
                wred[d] += __shfl_xor(wred[d], m);
        if (lane == 0) {
#pragma unroll
            for (int d = 0; d < 16; d++) redm[wv * 16 + d] = wred[d];
        }
    }
    __syncthreads();
    if (r < 16) {
        float s = 0.f;
#pragma unroll
        for (int w = 0; w < 16; w++) s += redm[w * 16 + r];
        ginv[r] = 1.f / s;
    }
    __syncthreads();
#pragma unroll
    for (int d = 0; d < 16; d++) mx[d] *= ginv[d];   // mx = softmax sm[r][d]

    // ---- 3) add phase (part 1) ----
    float asum = 0.f;
    {
        float4 a0 = base[4096 + r * 4 + 0];
        float4 a1 = base[4096 + r * 4 + 1];
        float4 a2 = base[4096 + r * 4 + 2];
        float4 a3 = base[4096 + r * 4 + 3];
        float av[16];
        av[0] = a0.x; av[1] = a0.y; av[2] = a0.z; av[3] = a0.w;
        av[4] = a1.x; av[5] = a1.y; av[6] = a1.z; av[7] = a1.w;
        av[8] = a2.x; av[9] = a2.y; av[10] = a2.z; av[11] = a2.w;
        av[12] = a3.x; av[13] = a3.y; av[14] = a3.z; av[15] = a3.w;
#pragma unroll
        for (int d = 0; d < 16; d++) asum += tanh_fast(av[d]) * mx[d];
    }
    addsum[(size_t)bc * 1024 + r] = asum;
    sred[r] = asum;

    // ---- 4) mul phase (part 0) ----
    float mv[16];
    {
        float4 m0 = base[r * 4 + 0];
        float4 m1 = base[r * 4 + 1];
        float4 m2 = base[r * 4 + 2];
        float4 m3 = base[r * 4 + 3];
        mv[0] = m0.x; mv[1] = m0.y; mv[2] = m0.z; mv[3] = m0.w;
        mv[4] = m1.x; mv[5] = m1.y; mv[6] = m1.z; mv[7] = m1.w;
        mv[8] = m2.x; mv[9] = m2.y; mv[10] = m2.z; mv[11] = m2.w;
        mv[12] = m3.x; mv[13] = m3.y; mv[14] = m3.z; mv[15] = m3.w;
#pragma unroll
        for (int d = 0; d < 16; d++) mv[d] = tanh_fast(mv[d]) * mx[d];
    }
    {
        float4* mp = reinterpret_cast<float4*>(&mulp[((size_t)bc * 1024 + r) * 16]);
        mp[0] = make_float4(mv[0], mv[1], mv[2], mv[3]);
        mp[1] = make_float4(mv[4], mv[5], mv[6], mv[7]);
        mp[2] = make_float4(mv[8], mv[9], mv[10], mv[11]);
        mp[3] = make_float4(mv[12], mv[13], mv[14], mv[15]);
    }
#pragma unroll
    for (int d = 0; d < 16; d++) mvl[d * MVL_STRIDE + r] = mv[d];
    __syncthreads();

    // ---- 5) A[dd][d], sv[dd] ----
    if (r < 256) {
        int dd = r >> 4, d = r & 15;
        int di = dd >> 2, dj = dd & 3;
        const float* bse = &mvl[d * MVL_STRIDE + di * 256 + dj * 8];
        float s = 0.f;
        for (int a = 0; a < 8; a++) {
#pragma unroll
            for (int e = 0; e < 8; e++) s += bse[a * 32 + e];
        }
        Ash[r] = s * (1.f / 64.f);
    }
    if (r < 16) {
        int di = r >> 2, dj = r & 3;
        float s = 0.f;
        for (int a = 0; a < 8; a++)
#pragma unroll
            for (int e = 0; e < 8; e++) s += sred[di * 256 + a * 32 + dj * 8 + e];
        svl[r] = s * (1.f / 64.f);
    }
    __syncthreads();

    // ---- 6) p_8 iteration on wave 0, 16-lane shfl broadcast ----
    if (r < 64) {
        int d2 = r & 15;
        float arow[16];
#pragma unroll
        for (int d = 0; d < 16; d++) arow[d] = Ash[d2 * 16 + d];
        float sv = svl[d2];
        float pd = 0.f;
        for (int it = 0; it < 8; it++) {
            float x = sv;
#pragma unroll
            for (int d = 0; d < 16; d++) x += arow[d] * __shfl(pd, d, 16);
            pd = x;
        }
        if (r < 16) pl[r] = pd;
    }
    __syncthreads();

    // ---- 7) q[r] ----
    {
        float x = asum;
#pragma unroll
        for (int d = 0; d < 16; d++) x += mv[d] * pl[d];
        q[(size_t)bc * 1024 + r] = x;
    }
}

// K5: final image. Block = (b, ri): 8 rows x 256 cols x 3 c. q staged in LDS.
__global__ __launch_bounds__(512) void k5_final(const float* __restrict__ mulp,
                                                const float* __restrict__ addsum,
                                                const float* __restrict__ q,
                                                float* __restrict__ out) {
    int blk = blockIdx.x;                 // 256
    int b = blk >> 5, ri = blk & 31;
    int tid = threadIdx.x;                // 512
    __shared__ float ql[3072];            // q for 3 channels of this b
    for (int i = tid; i < 3072; i += 512) ql[i] = q[(size_t)b * 3072 + i];
    __syncthreads();

    int h = tid >> 6;                     // 0..7 (wave-uniform)
    int rj = (tid >> 1) & 31;             // 0..31
    int wh = tid & 1;                     // w-half
    int r = ri * 32 + rj;

    float mr[3][16];
    float as[3];
#pragma unroll
    for (int c = 0; c < 3; c++) {
        const float4* mp4 = reinterpret_cast<const float4*>(
            &mulp[((size_t)(b * 3 + c) * 1024 + r) * 16]);
        float4 v0 = mp4[0], v1 = mp4[1], v2 = mp4[2], v3 = mp4[3];
        mr[c][0] = v0.x; mr[c][1] = v0.y; mr[c][2] = v0.z; mr[c][3] = v0.w;
        mr[c][4] = v1.x; mr[c][5] = v1.y; mr[c][6] = v1.z; mr[c][7] = v1.w;
        mr[c][8] = v2.x; mr[c][9] = v2.y; mr[c][10] = v2.z; mr[c][11] = v2.w;
        mr[c][12] = v3.x; mr[c][13] = v3.y; mr[c][14] = v3.z; mr[c][15] = v3.w;
        as[c] = addsum[(size_t)(b * 3 + c) * 1024 + r];
    }

    float acc[3][4];
#pragma unroll
    for (int c = 0; c < 3; c++)
#pragma unroll
        for (int w = 0; w < 4; w++) acc[c][w] = as[c];

#pragma unroll
    for (int di = 0; di < 4; di++) {
        int qrow = (di * 8 + h) * 32;
#pragma unroll
        for (int dj = 0; dj < 4; dj++) {
#pragma unroll
            for (int c = 0; c < 3; c++) {
                float m = mr[c][di * 4 + dj];
                const float* qb = &ql[c * 1024 + qrow + dj * 8 + wh * 4];
                acc[c][0] += m * qb[0];
                acc[c][1] += m * qb[1];
                acc[c][2] += m * qb[2];
                acc[c][3] += m * qb[3];
            }
        }
    }

    int i = ri * 8 + h;
    int j0 = rj * 8 + wh * 4;
    float4* ob = reinterpret_cast<float4*>(
        &out[((size_t)(b * 256 + i) * 256 + j0) * 3]);
    ob[0] = make_float4(acc[0][0], acc[1][0], acc[2][0], acc[0][1]);
    ob[1] = make_float4(acc[1][1], acc[2][1], acc[0][2], acc[1][2]);
    ob[2] = make_float4(acc[2][2], acc[0][3], acc[1][3], acc[2][3]);
}

extern "C" void kernel_launch(void* const* d_in, const int* in_sizes, int n_in,
                              void* d_out, int out_size, void* d_ws, size_t ws_size,
                              hipStream_t stream) {
    const float* pe = (const float*)d_in[0];   // (8,8,8,256)
    const float* w  = (const float*)d_in[1];   // (256,147456)
    const float* bt = (const float*)d_in[2];   // (147456,)
    float* ws = (float*)d_ws;

    float* me     = ws + OFF_ME;
    float* tt     = ws + OFF_THETA;
    float* mulp   = ws + OFF_MULP;
    float* addsum = ws + OFF_ADDSUM;
    float* q      = ws + OFF_Q;
    float* out = (float*)d_out;

    k1_mean<<<8, 1024, 0, stream>>>(pe, me);
    k2_gemm<<<T_COLS / 192, 192, 0, stream>>>(w, bt, me, tt);   // 768 blocks, XCD-swizzled
    kC<<<24, 1024, 0, stream>>>(tt, mulp, addsum, q);
    k5_final<<<256, 512, 0, stream>>>(mulp, addsum, q, out);
}